// Round 8
// baseline (180.209 us; speedup 1.0000x reference)
//
#include <hip/hip_runtime.h>
#include <hip/hip_bf16.h>

// TwoLayerGraphSAGE on MI355X.
//   Bucketed counting-sort CSR build -> MFMA indicator-SpMM aggregation -> fused MFMA GEMMs.
// Layer-1 aggregation gathers fp8(e4m3) rows; layer-2 aggregation bf16.
// R4: full-row coalesced gathers (8 lanes x 16B = one 128B line per row), 1 wave/block.
// R7: k_mfma12 XOR-granule-swizzled staging (bank conflicts 5.2M -> 0), 48KB, 3 blk/CU.
// R8: agg kernels DOUBLE-BUFFER the gather staging (2 x 4KB) with counted vmcnt:
// chunk ch+1's gathers are in flight while chunk ch computes; meta prefetched 2 ahead
// and issued BEFORE the gathers so the steady-state wait is vmcnt(6) (4 gathers + 2
// meta outstanding), vmcnt(2) on the last chunk. R2 tried this on 4-wave blocks and
// occupancy halved (confound); with 1-wave/8KB blocks the occupancy cost is ~nil.

#define N_NODES 100000
#define NGRP 6250         // N/16 node groups
#define NBKT 391          // ceil(100000/256) buckets of 256 dst nodes
#define ECHUNK 8192       // edges per block in hist/scatter
#define BCAP 12288        // LDS staging capacity per bucket
#define NXB 12500         // x-convert blocks
#define NWB 192           // weight-split blocks

typedef __attribute__((ext_vector_type(8))) short short8v;
typedef __attribute__((ext_vector_type(4))) float f32x4;
typedef __attribute__((ext_vector_type(2))) uint u32x2;

__device__ inline ushort bf16_rne(float f) {
    union { float f; uint u; } c; c.f = f;
    uint u = c.u;
    return (ushort)((u + 0x7FFFu + ((u >> 16) & 1u)) >> 16);
}
__device__ inline float bf16_f(ushort h) {
    union { uint u; float f; } c; c.u = (uint)h << 16;
    return c.f;
}
// f32 -> fp8 e4m3fn, RNE
__device__ inline unsigned char fp8_enc(float f) {
    union { float f; uint u; } c; c.f = f;
    uint u = c.u;
    uint s = (u >> 24) & 0x80u;
    uint a = u & 0x7FFFFFFFu;
    uint code;
    if (a >= 0x3C800000u) {
        uint r = a + 0x7FFFFu + ((a >> 20) & 1u);
        int e = (int)(r >> 23) - 120;
        uint mm = (r >> 20) & 7u;
        code = ((uint)e << 3) | mm;
        if (code > 0x7Eu) code = 0x7Eu;
    } else {
        code = (uint)(__uint_as_float(a) * 512.0f + 0.5f);
    }
    return (unsigned char)(s | code);
}

__device__ inline void gl_lds16(const void* g, void* l) {
    __builtin_amdgcn_global_load_lds(
        (const __attribute__((address_space(1))) uint*)g,
        (__attribute__((address_space(3))) uint*)l, 16, 0, 0);
}
__device__ inline uint lds_off(const void* p) {
    return (uint)(size_t)(const __attribute__((address_space(3))) char*)p;
}

// ---------------- fused prep: x->bf16+fp8 | weight split | bucket histogram ----------------
__global__ __launch_bounds__(256) void k_prep(const float* __restrict__ x,
                                              const float* __restrict__ W1l,
                                              const float* __restrict__ W1r,
                                              const float* __restrict__ W2l,
                                              const float* __restrict__ W2r,
                                              const int* __restrict__ dst, int E,
                                              ushort* __restrict__ xh,
                                              unsigned char* __restrict__ xf8,
                                              ushort* __restrict__ BT1h,
                                              ushort* __restrict__ BT1l,
                                              ushort* __restrict__ BT2h,
                                              ushort* __restrict__ BT2l,
                                              int* __restrict__ bhist) {
    __shared__ int hsh[NBKT];
    const int b = blockIdx.x;
    if (b < NXB) {
        int i = (b * 256 + threadIdx.x) * 4;
        float4 v = *(const float4*)&x[i];
        ushort4 hh;
        hh.x = bf16_rne(v.x); hh.y = bf16_rne(v.y);
        hh.z = bf16_rne(v.z); hh.w = bf16_rne(v.w);
        *(ushort4*)&xh[i] = hh;
        uint f8 = (uint)fp8_enc(v.x) | ((uint)fp8_enc(v.y) << 8) |
                  ((uint)fp8_enc(v.z) << 16) | ((uint)fp8_enc(v.w) << 24);
        *(uint*)&xf8[i] = f8;
    } else if (b < NXB + NWB) {
        int id = (b - NXB) * 256 + threadIdx.x;
        if (id < 32768) {
            int n = id >> 8, k = id & 255;
            float v = (k < 128) ? W1l[k * 128 + n] : W1r[(k - 128) * 128 + n];
            ushort h = bf16_rne(v);
            BT1h[id] = h;
            BT1l[id] = bf16_rne(v - bf16_f(h));
        } else {
            int i = id - 32768;
            int n = i >> 7, k = i & 127;
            float v = (n < 64) ? W2l[k * 64 + n] : W2r[k * 64 + (n - 64)];
            ushort h = bf16_rne(v);
            BT2h[i] = h;
            BT2l[i] = bf16_rne(v - bf16_f(h));
        }
    } else {
        int bb = b - NXB - NWB;
        for (int i = threadIdx.x; i < NBKT; i += 256) hsh[i] = 0;
        __syncthreads();
        int b0 = bb * ECHUNK;
        for (int i = threadIdx.x; i < ECHUNK; i += 256) {
            int e = b0 + i;
            if (e < E) atomicAdd(&hsh[dst[e] >> 8], 1);
        }
        __syncthreads();
        for (int i = threadIdx.x; i < NBKT; i += 256)
            if (hsh[i]) atomicAdd(&bhist[i], hsh[i]);
    }
}

// ---------------- A2: scan bucket totals ----------------
__global__ __launch_bounds__(512) void kA2_scan(const int* __restrict__ bhist,
                                                int* __restrict__ boff,
                                                int* __restrict__ bcur) {
    __shared__ int s[512];
    int t = threadIdx.x;
    s[t] = (t < NBKT) ? bhist[t] : 0;
    __syncthreads();
    for (int d = 1; d < 512; d <<= 1) {
        int v = (t >= d) ? s[t - d] : 0;
        __syncthreads();
        s[t] += v;
        __syncthreads();
    }
    if (t <= NBKT) {
        int e = (t == 0) ? 0 : s[t - 1];
        boff[t] = e;
        if (t < NBKT) bcur[t] = e;
    }
}

// ---------------- A3: scatter packed (src | dlow<<17) ----------------
__global__ __launch_bounds__(256) void kA3_scatter(const int* __restrict__ src,
                                                   const int* __restrict__ dst,
                                                   int* __restrict__ bcur,
                                                   int* __restrict__ pairs, int E) {
    __shared__ int hist[NBKT];
    __shared__ int base[NBKT];
    __shared__ ushort rank[ECHUNK];
    for (int i = threadIdx.x; i < NBKT; i += 256) hist[i] = 0;
    __syncthreads();
    int b0 = blockIdx.x * ECHUNK;
    for (int i = threadIdx.x; i < ECHUNK; i += 256) {
        int e = b0 + i;
        if (e < E) rank[i] = (ushort)atomicAdd(&hist[dst[e] >> 8], 1);
    }
    __syncthreads();
    for (int i = threadIdx.x; i < NBKT; i += 256) {
        int c = hist[i];
        base[i] = c ? atomicAdd(&bcur[i], c) : 0;
    }
    __syncthreads();
    for (int i = threadIdx.x; i < ECHUNK; i += 256) {
        int e = b0 + i;
        if (e < E) {
            int d = dst[e];
            pairs[base[d >> 8] + rank[i]] = src[e] | ((d & 255) << 17);
        }
    }
}

// ---------------- B: per-bucket sort -> csr, ldst, offsets, invdeg ----------------
// R3 sort key: (group_in_bucket<<4) | (src>>13) -- group-major, then src ranges.
__global__ __launch_bounds__(256) void kB_build(const int* __restrict__ pairs,
                                                const int* __restrict__ boff,
                                                int* __restrict__ csr,
                                                unsigned char* __restrict__ ldst,
                                                int* __restrict__ offsets,
                                                float* __restrict__ invdeg,
                                                int N, int E) {
    __shared__ int cntk[256];   // key8 histogram (sort key)
    __shared__ int sck[256];    // inclusive scan of cntk
    __shared__ int cur[256];
    __shared__ int cntn[256];   // per-local-node degree
    __shared__ int stage[BCAP];
    const int b = blockIdx.x;
    const int gbase = boff[b], gcount = boff[b + 1] - gbase;
    const int n0 = b << 8;
    const int t = threadIdx.x;

    cntk[t] = 0; cntn[t] = 0;
    __syncthreads();
    for (int i = t; i < gcount; i += 256) {
        int p = pairs[gbase + i];
        int dlow = (p >> 17) & 255;
        int key = (dlow & 0xF0) | ((p & 0x1FFFF) >> 13);
        atomicAdd(&cntk[key], 1);
        atomicAdd(&cntn[dlow], 1);
    }
    __syncthreads();
    sck[t] = cntk[t];
    __syncthreads();
    for (int d = 1; d < 256; d <<= 1) {
        int v = (t >= d) ? sck[t - d] : 0;
        __syncthreads();
        sck[t] += v;
        __syncthreads();
    }
    cur[t] = sck[t] - cntk[t];
    int node = n0 + t;
    if (node < N) {
        int gk = t & 0xF0;                       // group base key
        offsets[node] = gbase + sck[gk] - cntk[gk];
        invdeg[node] = 1.0f / fmaxf((float)cntn[t], 1.0f);
    }
    if (b == NBKT - 1 && t == 0) offsets[N] = E;
    __syncthreads();

    if (gcount <= BCAP) {
        for (int i = t; i < gcount; i += 256) {
            int p = pairs[gbase + i];
            int key = ((p >> 17) & 0xF0) | ((p & 0x1FFFF) >> 13);
            int pos = atomicAdd(&cur[key], 1);
            stage[pos] = p;
        }
        __syncthreads();
        for (int i = t; i < gcount; i += 256) {
            int p = stage[i];
            csr[gbase + i] = p & 0x1FFFF;
            ldst[gbase + i] = (unsigned char)((p >> 17) & 15);
        }
    } else {
        for (int i = t; i < gcount; i += 256) {
            int p = pairs[gbase + i];
            int key = ((p >> 17) & 0xF0) | ((p & 0x1FFFF) >> 13);
            int pos = atomicAdd(&cur[key], 1);
            csr[gbase + pos] = p & 0x1FFFF;
            ldst[gbase + pos] = (unsigned char)((p >> 17) & 15);
        }
    }
}

// ============ layer-1 MFMA indicator-SpMM aggregation, fp8 ============
// ONE 16-node group per BLOCK = per WAVE (64 threads). Double-buffered row-major
// swizzled staging (2 x 4KB): gathers for chunk ch+1 issued before computing chunk ch;
// meta prefetched 2 ahead and issued BEFORE the gathers. Steady-state wait vmcnt(6)
// (= 4 gathers(ch+1) + 2 meta(ch+2) outstanding -> gathers(ch) + meta(ch+1) landed);
// vmcnt(2) on the last chunk. tr_b8 reads from buf[ch&1].
__global__ __launch_bounds__(64, 8) void k_agg1(const unsigned char* __restrict__ xf8,
                                                const int* __restrict__ csr,
                                                const unsigned char* __restrict__ ldst,
                                                const int* __restrict__ off,
                                                const float* __restrict__ invdeg,
                                                ushort* __restrict__ ah, int E) {
    __shared__ __align__(1024) char stg[8192];   // 2 x 4KB
    const int lane = threadIdx.x;
    const int g = blockIdx.x;
    const int gbase = off[g * 16], gend = off[g * 16 + 16];
    const int cnt = gend - gbase;
    const int m = lane & 15;
    const int e_meta = lane & 31;
    const int Emax = E - 1;
    const int esrc = lane >> 3;
    const int koff = ((lane & 7) ^ (esrc & 7)) << 4;

    f32x4 acc[8] = {};
    const int nch = (cnt + 31) >> 5;

    // meta for chunks 0 and 1
    int p0 = gbase + e_meta;
    int se_cur = csr[(p0 < Emax) ? p0 : Emax];
    int lb_cur = (p0 < gend) ? (int)ldst[p0] : 255;
    int p1 = p0 + 32;
    int se_nxt = csr[(p1 < Emax) ? p1 : Emax];
    int lb_nxt = (p1 < gend) ? (int)ldst[p1] : 255;

    // gathers for chunk 0 -> buf0
    {
        #pragma unroll
        for (int c = 0; c < 4; ++c) {
            int rs = __shfl(se_cur, c * 8 + esrc);
            gl_lds16((const char*)xf8 + (size_t)rs * 128 + koff, stg + c * 1024);
        }
    }

    const uint e7 = (lane >> 1) & 7;
    const uint bbase0 = lds_off(stg) + (uint)((lane >> 1) * 128 + (lane & 1) * 8);

    for (int ch = 0; ch < nch; ++ch) {
        char* nxtb = stg + ((ch & 1) ? 0 : 4096);
        uint bbase = bbase0 + ((ch & 1) ? 4096u : 0u);

        // meta for ch+2, BEFORE the gathers (retire-wait folds into vmcnt(6))
        int p2 = gbase + (ch + 2) * 32 + e_meta;
        int se2 = csr[(p2 < Emax) ? p2 : Emax];
        int lb2 = (p2 < gend) ? (int)ldst[p2] : 255;
        __builtin_amdgcn_sched_barrier(0);
        if (ch + 1 < nch) {
            #pragma unroll
            for (int c = 0; c < 4; ++c) {
                int rs = __shfl(se_nxt, c * 8 + esrc);
                gl_lds16((const char*)xf8 + (size_t)rs * 128 + koff, nxtb + c * 1024);
            }
            asm volatile("s_waitcnt vmcnt(6)" ::: "memory");   // chunk ch's gathers landed
        } else {
            asm volatile("s_waitcnt vmcnt(2)" ::: "memory");
        }
        __builtin_amdgcn_sched_barrier(0);

        unsigned long long av = 0ull;
        #pragma unroll
        for (int j = 0; j < 8; ++j) {
            int k = (lane >> 4) * 8 + j;
            int b = __shfl(lb_cur, k);
            av |= (b == m) ? (0x38ull << (8 * j)) : 0ull;
        }

        #pragma unroll
        for (int th = 0; th < 2; ++th) {
            u32x2 tb[4];
            #pragma unroll
            for (int t4 = 0; t4 < 4; ++t4) {
                uint t = (uint)(th * 4 + t4);
                uint a1 = bbase + ((t ^ e7) << 4);
                asm volatile("ds_read_b64_tr_b8 %0, %1" : "=v"(tb[t4]) : "v"(a1));
            }
            asm volatile("s_waitcnt lgkmcnt(0)" ::: "memory");
            __builtin_amdgcn_sched_barrier(0);
            #pragma unroll
            for (int t4 = 0; t4 < 4; ++t4) {
                unsigned long long bv = ((unsigned long long)tb[t4].y << 32) | tb[t4].x;
                acc[th * 4 + t4] = __builtin_amdgcn_mfma_f32_16x16x32_fp8_fp8(
                    (long long)av, (long long)bv, acc[th * 4 + t4], 0, 0, 0);
            }
            __builtin_amdgcn_sched_barrier(0);  // keep halves separate (reg reuse)
        }
        se_nxt = se2; lb_cur = lb_nxt; lb_nxt = lb2;
    }

    float idv[4];
    #pragma unroll
    for (int i = 0; i < 4; ++i) idv[i] = invdeg[g * 16 + (lane >> 4) * 4 + i];
    #pragma unroll
    for (int t = 0; t < 8; ++t) {
        #pragma unroll
        for (int i = 0; i < 4; ++i) {
            int node = g * 16 + (lane >> 4) * 4 + i;
            ah[(size_t)node * 128 + t * 16 + m] = bf16_rne(acc[t][i] * idv[i]);
        }
    }
}

// ============ layer-2 aggregation + combine (bf16, tr_b16), same double-buffered scheme ============
__global__ __launch_bounds__(64, 8) void k_agg2(const ushort* __restrict__ hWl,
                                                const float* __restrict__ hWr,
                                                const int* __restrict__ csr,
                                                const unsigned char* __restrict__ ldst,
                                                const int* __restrict__ off,
                                                const float* __restrict__ invdeg,
                                                const float* __restrict__ b2,
                                                float* __restrict__ out, int E) {
    __shared__ __align__(1024) char stg[8192];   // 2 x 4KB
    const int lane = threadIdx.x;
    const int g = blockIdx.x;
    const int gbase = off[g * 16], gend = off[g * 16 + 16];
    const int cnt = gend - gbase;
    const int m = lane & 15;
    const int e_meta = lane & 31;
    const int Emax = E - 1;
    const int esrc = lane >> 3;
    const int koff = ((lane & 7) ^ ((esrc & 3) << 1)) << 4;

    f32x4 acc[4] = {};
    const int nch = (cnt + 31) >> 5;

    int p0 = gbase + e_meta;
    int se_cur = csr[(p0 < Emax) ? p0 : Emax];
    int lb_cur = (p0 < gend) ? (int)ldst[p0] : 255;
    int p1 = p0 + 32;
    int se_nxt = csr[(p1 < Emax) ? p1 : Emax];
    int lb_nxt = (p1 < gend) ? (int)ldst[p1] : 255;

    {
        #pragma unroll
        for (int c = 0; c < 4; ++c) {
            int rs = __shfl(se_cur, c * 8 + esrc);
            gl_lds16((const char*)hWl + (size_t)rs * 128 + koff, stg + c * 1024);
        }
    }

    const uint he = ((lane >> 1) & 1) ^ (((lane >> 2) & 3) << 1);
    const uint bbase0 = lds_off(stg) +
        (uint)(((lane >> 4) * 8 + ((lane >> 2) & 3)) * 128 + (lane & 1) * 8);

    for (int ch = 0; ch < nch; ++ch) {
        char* nxtb = stg + ((ch & 1) ? 0 : 4096);
        uint bbase = bbase0 + ((ch & 1) ? 4096u : 0u);

        int p2 = gbase + (ch + 2) * 32 + e_meta;
        int se2 = csr[(p2 < Emax) ? p2 : Emax];
        int lb2 = (p2 < gend) ? (int)ldst[p2] : 255;
        __builtin_amdgcn_sched_barrier(0);
        if (ch + 1 < nch) {
            #pragma unroll
            for (int c = 0; c < 4; ++c) {
                int rs = __shfl(se_nxt, c * 8 + esrc);
                gl_lds16((const char*)hWl + (size_t)rs * 128 + koff, nxtb + c * 1024);
            }
            asm volatile("s_waitcnt vmcnt(6)" ::: "memory");
        } else {
            asm volatile("s_waitcnt vmcnt(2)" ::: "memory");
        }
        __builtin_amdgcn_sched_barrier(0);

        uint au[4];
        #pragma unroll
        for (int jp = 0; jp < 4; ++jp) {
            int k0 = (lane >> 4) * 8 + jp * 2;
            int b0 = __shfl(lb_cur, k0);
            int b1 = __shfl(lb_cur, k0 + 1);
            au[jp] = ((b0 == m) ? 0x3F80u : 0u) | (((b1 == m) ? 0x3F80u : 0u) << 16);
        }
        union { uint u[4]; short8v v; } A_;
        A_.u[0] = au[0]; A_.u[1] = au[1]; A_.u[2] = au[2]; A_.u[3] = au[3];

        #pragma unroll
        for (int th = 0; th < 2; ++th) {
            u32x2 t1[2], t2[2];
            #pragma unroll
            for (int tt = 0; tt < 2; ++tt) {
                uint t = (uint)(th * 2 + tt);
                uint seg = (2u * t) ^ he;
                uint a1 = bbase + (seg << 4);
                uint a2 = a1 + 512;
                asm volatile("ds_read_b64_tr_b16 %0, %1" : "=v"(t1[tt]) : "v"(a1));
                asm volatile("ds_read_b64_tr_b16 %0, %1" : "=v"(t2[tt]) : "v"(a2));
            }
            asm volatile("s_waitcnt lgkmcnt(0)" ::: "memory");
            __builtin_amdgcn_sched_barrier(0);
            #pragma unroll
            for (int tt = 0; tt < 2; ++tt) {
                union { uint u[4]; short8v v; } B_;
                B_.u[0] = t1[tt].x; B_.u[1] = t1[tt].y;
                B_.u[2] = t2[tt].x; B_.u[3] = t2[tt].y;
                acc[th * 2 + tt] = __builtin_amdgcn_mfma_f32_16x16x32_bf16(
                    A_.v, B_.v, acc[th * 2 + tt], 0, 0, 0);
            }
            __builtin_amdgcn_sched_barrier(0);  // keep halves separate (reg reuse)
        }
        se_nxt = se2; lb_cur = lb_nxt; lb_nxt = lb2;
    }

    float idv[4];
    #pragma unroll
    for (int i = 0; i < 4; ++i) idv[i] = invdeg[g * 16 + (lane >> 4) * 4 + i];
    #pragma unroll
    for (int t = 0; t < 4; ++t) {
        #pragma unroll
        for (int i = 0; i < 4; ++i) {
            int node = g * 16 + (lane >> 4) * 4 + i;
            size_t idx = (size_t)node * 64 + t * 16 + m;
            out[idx] = acc[t][i] * idv[i] + hWr[idx] + b2[t * 16 + m];
        }
    }
}

// ---------------- fused MFMA GEMM: layer1 -> h (LDS) -> layer2 ----------------
// R7: 64B rows + XOR granule swizzle. Granule (r,q) stored at r*64 + (q^((r>>1)&3))*16.
// Swizzle applied via each thread's GLOBAL source quarter (q0/q1); write addresses are
// linear (r*64 + cq*16) -> per-8-lane-phase writes AND reads cover all 32 banks.
// Reg-prefetch pipeline (verified structure); hT (32KB, same swizzle) overlaps dead Ah;
// total 48KB -> 3 blocks/CU. Phase-2 hT read = AhT[kc*4096 + aof[f]] (swizzle algebra:
// f(kc*128+ra) == f(ra) since 64*kc % 4 == 0).
__global__ __launch_bounds__(256, 3) void k_mfma12(
    const ushort* __restrict__ Agg, const ushort* __restrict__ X,
    const ushort* __restrict__ B1h, const ushort* __restrict__ B1l,
    const ushort* __restrict__ B2h, const ushort* __restrict__ B2l,
    const float* __restrict__ b1,
    ushort* __restrict__ hWl, float* __restrict__ hWr, int M) {
    __shared__ ushort SM[24576];            // 48KB
    ushort* Bh  = SM;                       // [0, 4096)
    ushort* Bl  = SM + 4096;                // [4096, 8192)
    ushort* AhT = SM + 8192;                // Ah (phase 1, 8KB) / hT (phase 2, 32KB)

    const int tid = threadIdx.x;
    const int wid = tid >> 6, lane = tid & 63;
    const int wm = wid >> 1, wn = wid & 1;
    const int m0 = blockIdx.x * 128;
    const int rl = lane & 15, kq = lane >> 4;
    const int rq = kq;

    const int r0 = tid >> 2, r1 = r0 + 64;
    const int cq = tid & 3;
    int g0 = m0 + r0; if (g0 >= M) g0 = M - 1;
    int g1 = m0 + r1; if (g1 >= M) g1 = M - 1;
    const int q0 = (cq ^ ((r0 >> 1) & 3)) * 8;   // swizzled source quarter (ushorts)
    const int q1 = (cq ^ ((r1 >> 1) & 3)) * 8;
    const int ldso0 = r0 * 32 + cq * 8;          // linear write slot (ushorts)
    const int ldso1 = r1 * 32 + cq * 8;

    // loop-invariant swizzled fragment-read offsets (ushorts)
    int aof[4], bof[4];
    #pragma unroll
    for (int f = 0; f < 4; ++f) {
        int ra = wm * 64 + f * 16 + rl;
        int rb = wn * 64 + f * 16 + rl;
        aof[f] = ra * 32 + ((kq ^ ((ra >> 1) & 3)) << 3);
        bof[f] = rb * 32 + ((kq ^ ((rb >> 1) & 3)) << 3);
    }

    // ---------- phase 1: K=256 over [agg | x], pipelined ----------
    short8v pA0, pA1, pB0, pB1, pL0, pL1;
    {
        // kc=0: gk = q0/q1 < 32 -> Agg
        pA0 = *(const short8v*)&Agg[(size_t)g0 * 128 + q0];
        pA1 = *(const short8v*)&Agg[(size_t)g1 * 128 + q1];
        pB0 = *(const short8v*)&B1h[r0 * 256 + q0];
        pB1 = *(const short8v*)&B1h[r1 * 256 + q1];
        pL0 = *(const short8v*)&B1l[r0 * 256 + q0];
        pL1 = *(const short8v*)&B1l[r1 * 256 + q1];
    }
    f32x4 acc[4][4] = {};
    for (int kc = 0; kc < 8; ++kc) {
        *(short8v*)&AhT[ldso0] = pA0; *(short8v*)&AhT[ldso1] = pA1;
        *(short8v*)&Bh[ldso0]  = pB0; *(short8v*)&Bh[ldso1]  = pB1;
        *(short8v*)&Bl[ldso0]  = pL0; *(short8v*)&Bl[ldso1]  = pL1;
        __syncthreads();

        if (kc < 7) {   // issue kc+1 loads before the MFMA cluster (T14)
            int gk0 = (kc + 1) * 32 + q0;
            int gk1 = (kc + 1) * 32 + q1;
            // q* <= 24 < 32, so gk >= 128 iff kc+1 >= 4: uniform per unrolled iter.
            const ushort* s0 = (kc + 1 >= 4) ? &X[(size_t)g0 * 128 + gk0 - 128]
                                             : &Agg[(size_t)g0 * 128 + gk0];
            const ushort* s1 = (kc + 1 >= 4) ? &X[(size_t)g1 * 128 + gk1 - 128]
                                             : &Agg[(size_t)g1 * 128 + gk1];
            pA0 = *(const short8v*)s0;
            pA1 = *(const short8v*)s1;
            pB0 = *(const short8v*)&B1h[r0 * 256 + gk0];
            pB1 = *(const short8v*)&B1h[r1 * 256 + gk1];
            pL0 = *(const short8v*)&B1l[r0 * 256 + gk0];
            pL1 = *(const short8v*)&B1l[r1 * 256 + gk1];
        }

        short8v a_h[4], b_h[4], b_l[4];
        #pragma unroll
        for (int f = 0; f < 4; ++f) {
            a_h[f] = *(const short8v*)&AhT[aof[f]];
            b_h[f] = *(const short8v*)&Bh[bof[f]];
            b_l[f] = *(const short8v*)&Bl[bof[f]];
        }
        #pragma unroll
        for (int mf = 0; mf < 4; ++mf)
            #pragma unroll
            for (int nf = 0; nf < 4; ++nf) {
                acc[mf][nf] = __builtin_amdgcn_mfma_f32_16x16x32_bf16(a_h[mf], b_h[nf], acc[mf][nf], 0, 0, 0);
                acc[mf][nf] = __builtin_amdgcn_mfma_f32_16x16x32_bf16(a_h[mf], b_l[nf], acc[mf][nf], 0, 0, 0);
            }
        __syncthreads();
    }

    // ---------- phase-2 kc=0 B loads issued early (hide under hT writes) ----------
    short8v qB0, qB1, qL0, qL1;
    {
        qB0 = *(const short8v*)&B2h[r0 * 128 + q0];
        qB1 = *(const short8v*)&B2h[r1 * 128 + q1];
        qL0 = *(const short8v*)&B2l[r0 * 128 + q0];
        qL1 = *(const short8v*)&B2l[r1 * 128 + q1];
    }

    // ---------- h tile -> LDS (relu + bias, bf16), swizzled 64B rows ----------
    #pragma unroll
    for (int mf = 0; mf < 4; ++mf)
        #pragma unroll
        for (int nf = 0; nf < 4; ++nf) {
            int col = wn * 64 + nf * 16 + rl;
            float bv = b1[col];
            int cc = col >> 5;
            int ic = col & 31;
            int gq = ic >> 3;
            #pragma unroll
            for (int i = 0; i < 4; ++i) {
                int rloc = wm * 64 + mf * 16 + rq * 4 + i;
                float v = fmaxf(acc[mf][nf][i] + bv, 0.0f);
                int rho = cc * 128 + rloc;
                AhT[rho * 32 + ((gq ^ ((rloc >> 1) & 3)) << 3) + (ic & 7)] = bf16_rne(v);
            }
        }
    __syncthreads();

    // ---------- phase 2: K=128 over h, pipelined ----------
    f32x4 acc2[4][4] = {};
    for (int kc = 0; kc < 4; ++kc) {
        *(short8v*)&Bh[ldso0] = qB0; *(short8v*)&Bh[ldso1] = qB1;
        *(short8v*)&Bl[ldso0] = qL0; *(short8v*)&Bl[ldso1] = qL1;
        __syncthreads();

        if (kc < 3) {
            int gk0 = (kc + 1) * 32 + q0;
            int gk1 = (kc + 1) * 32 + q1;
            qB0 = *(const short8v*)&B2h[r0 * 128 + gk0];
            qB1 = *(const short8v*)&B2h[r1 * 128 + gk1];
            qL0 = *(const short8v*)&B2l[r0 * 128 + gk0];
            qL1 = *(const short8v*)&B2l[r1 * 128 + gk1];
        }

        short8v a_h[4], b_h[4], b_l[4];
        #pragma unroll
        for (int f = 0; f < 4; ++f) {
            a_h[f] = *(const short8v*)&AhT[kc * 4096 + aof[f]];
            b_h[f] = *(const short8v*)&Bh[bof[f]];
            b_l[f] = *(const short8v*)&Bl[bof[f]];
        }
        #pragma unroll
        for (int mf = 0; mf < 4; ++mf)
            #pragma unroll
            for (int nf = 0; nf < 4; ++nf) {
                acc2[mf][nf] = __builtin_amdgcn_mfma_f32_16x16x32_bf16(a_h[mf], b_h[nf], acc2[mf][nf], 0, 0, 0);
                acc2[mf][nf] = __builtin_amdgcn_mfma_f32_16x16x32_bf16(a_h[mf], b_l[nf], acc2[mf][nf], 0, 0, 0);
            }
        __syncthreads();
    }

    // ---------- epilogue: hWl (bf16) | hWr (f32) ----------
    #pragma unroll
    for (int mf = 0; mf < 4; ++mf)
        #pragma unroll
        for (int nf = 0; nf < 4; ++nf) {
            int col = wn * 64 + nf * 16 + rl;
            #pragma unroll
            for (int i = 0; i < 4; ++i) {
                int row = m0 + wm * 64 + mf * 16 + rq * 4 + i;
                if (row < M) {
                    float v = acc2[mf][nf][i];
                    if (col < 64) hWl[(size_t)row * 64 + col] = bf16_rne(v);
                    else          hWr[(size_t)row * 64 + col - 64] = v;
                }
            }
        }
}

extern "C" void kernel_launch(void* const* d_in, const int* in_sizes, int n_in,
                              void* d_out, int out_size, void* d_ws, size_t ws_size,
                              hipStream_t stream) {
    const float* x   = (const float*)d_in[0];
    const int*   ei  = (const int*)d_in[1];
    const float* W1l = (const float*)d_in[3];
    const float* W1r = (const float*)d_in[4];
    const float* b1  = (const float*)d_in[5];
    const float* W2l = (const float*)d_in[6];
    const float* W2r = (const float*)d_in[7];
    const float* b2  = (const float*)d_in[8];
    float* out = (float*)d_out;

    const int N = N_NODES;
    const int E = in_sizes[1] / 2;     // 1,600,000
    const int* src = ei;
    const int* dst = ei + E;
    const int NEB = (E + ECHUNK - 1) / ECHUNK;   // 196

    // workspace layout (bytes)
    char* ws = (char*)d_ws;
    int*           bhist   = (int*)   (ws + 0);
    int*           boff    = (int*)   (ws + 4096);
    int*           bcur    = (int*)   (ws + 8192);
    int*           offsets = (int*)   (ws + 12288);      // N+1
    float*         invdeg  = (float*) (ws + 417792);     // N
    int*           csr     = (int*)   (ws + 819200);     // E ints (6.4MB)
    unsigned char* ldst    = (unsigned char*)(ws + 7220224);  // E bytes (1.6MB)
    unsigned char* x_f8    = (unsigned char*)(ws + 8821760);  // N*128 fp8 (12.8MB)
    ushort*        x_hi    = (ushort*)(ws + 21622784);   // 25.6MB
    ushort*        agg_hi  = (ushort*)(ws + 47223808);   // 25.6MB
    float*         hWr     = (float*) (ws + 98425856);   // 25.6MB
    ushort*        BT1h    = (ushort*)(ws + 124026880);  // 64KB
    ushort*        BT1l    = (ushort*)(ws + 124092416);
    ushort*        BT2h    = (ushort*)(ws + 124157952);  // 32KB
    ushort*        BT2l    = (ushort*)(ws + 124190720);
    // pairs (packed int, 6.4MB) aliases the hWr slot (dead before mfma12 writes hWr)
    int*           pairs   = (int*)   (ws + 98425856);
    // hWl lives in its own slot (must not alias agg: mfma12 reads agg while writing hWl)
    ushort*        hWl     = (ushort*)(ws + 72824832);   // 12.8MB used

    hipMemsetAsync(bhist, 0, NBKT * 4, stream);

    k_prep<<<NXB + NWB + NEB, 256, 0, stream>>>(x, W1l, W1r, W2l, W2r, dst, E,
                                                x_hi, x_f8, BT1h, BT1l, BT2h, BT2l, bhist);
    kA2_scan<<<1, 512, 0, stream>>>(bhist, boff, bcur);
    kA3_scatter<<<NEB, 256, 0, stream>>>(src, dst, bcur, pairs, E);
    kB_build<<<NBKT, 256, 0, stream>>>(pairs, boff, csr, ldst, offsets, invdeg, N, E);

    k_agg1<<<NGRP, 64, 0, stream>>>(x_f8, csr, ldst, offsets, invdeg, agg_hi, E);

    const int MB = (N + 127) / 128;    // 782
    k_mfma12<<<MB, 256, 0, stream>>>(agg_hi, x_hi, BT1h, BT1l, BT2h, BT2l,
                                     b1, hWl, hWr, N);

    k_agg2<<<NGRP, 64, 0, stream>>>(hWl, hWr, csr, ldst, offsets, invdeg, b2, out, E);
}

// Round 9
// 175.624 us; speedup vs baseline: 1.0261x; 1.0261x over previous
//
#include <hip/hip_runtime.h>
#include <hip/hip_bf16.h>

// TwoLayerGraphSAGE on MI355X.
//   Bucketed counting-sort CSR build -> MFMA indicator-SpMM aggregation -> fused MFMA GEMMs.
// Layer-1 aggregation gathers fp8(e4m3) rows; layer-2 aggregation bf16.
// R4: full-row coalesced gathers (8 lanes x 16B = one 128B line per row).
// R7: k_mfma12 XOR-granule-swizzled staging (bank conflicts 5.2M -> 0), 48KB, 3 blk/CU.
// R9: agg kernels re-packed as 256-thread blocks of 4 INDEPENDENT waves (4KB staging
// each, no barriers, per-wave body identical to R7's single-buffer vmcnt(0) scheme).
// 64-thread blocks hit the per-CU workgroup-slot cap (~16 blocks/CU -> <=16 waves/CU);
// 4-wave blocks allow ~24 resident waves/CU -- the TLP the latency-bound gather loop
// was missing. (R8's counted-vmcnt pipeline regressed and is reverted.)

#define N_NODES 100000
#define NGRP 6250         // N/16 node groups
#define NBKT 391          // ceil(100000/256) buckets of 256 dst nodes
#define ECHUNK 8192       // edges per block in hist/scatter
#define BCAP 12288        // LDS staging capacity per bucket
#define NXB 12500         // x-convert blocks
#define NWB 192           // weight-split blocks

typedef __attribute__((ext_vector_type(8))) short short8v;
typedef __attribute__((ext_vector_type(4))) float f32x4;
typedef __attribute__((ext_vector_type(2))) uint u32x2;

__device__ inline ushort bf16_rne(float f) {
    union { float f; uint u; } c; c.f = f;
    uint u = c.u;
    return (ushort)((u + 0x7FFFu + ((u >> 16) & 1u)) >> 16);
}
__device__ inline float bf16_f(ushort h) {
    union { uint u; float f; } c; c.u = (uint)h << 16;
    return c.f;
}
// f32 -> fp8 e4m3fn, RNE
__device__ inline unsigned char fp8_enc(float f) {
    union { float f; uint u; } c; c.f = f;
    uint u = c.u;
    uint s = (u >> 24) & 0x80u;
    uint a = u & 0x7FFFFFFFu;
    uint code;
    if (a >= 0x3C800000u) {
        uint r = a + 0x7FFFFu + ((a >> 20) & 1u);
        int e = (int)(r >> 23) - 120;
        uint mm = (r >> 20) & 7u;
        code = ((uint)e << 3) | mm;
        if (code > 0x7Eu) code = 0x7Eu;
    } else {
        code = (uint)(__uint_as_float(a) * 512.0f + 0.5f);
    }
    return (unsigned char)(s | code);
}

__device__ inline void gl_lds16(const void* g, void* l) {
    __builtin_amdgcn_global_load_lds(
        (const __attribute__((address_space(1))) uint*)g,
        (__attribute__((address_space(3))) uint*)l, 16, 0, 0);
}
__device__ inline uint lds_off(const void* p) {
    return (uint)(size_t)(const __attribute__((address_space(3))) char*)p;
}

// ---------------- fused prep: x->bf16+fp8 | weight split | bucket histogram ----------------
__global__ __launch_bounds__(256) void k_prep(const float* __restrict__ x,
                                              const float* __restrict__ W1l,
                                              const float* __restrict__ W1r,
                                              const float* __restrict__ W2l,
                                              const float* __restrict__ W2r,
                                              const int* __restrict__ dst, int E,
                                              ushort* __restrict__ xh,
                                              unsigned char* __restrict__ xf8,
                                              ushort* __restrict__ BT1h,
                                              ushort* __restrict__ BT1l,
                                              ushort* __restrict__ BT2h,
                                              ushort* __restrict__ BT2l,
                                              int* __restrict__ bhist) {
    __shared__ int hsh[NBKT];
    const int b = blockIdx.x;
    if (b < NXB) {
        int i = (b * 256 + threadIdx.x) * 4;
        float4 v = *(const float4*)&x[i];
        ushort4 hh;
        hh.x = bf16_rne(v.x); hh.y = bf16_rne(v.y);
        hh.z = bf16_rne(v.z); hh.w = bf16_rne(v.w);
        *(ushort4*)&xh[i] = hh;
        uint f8 = (uint)fp8_enc(v.x) | ((uint)fp8_enc(v.y) << 8) |
                  ((uint)fp8_enc(v.z) << 16) | ((uint)fp8_enc(v.w) << 24);
        *(uint*)&xf8[i] = f8;
    } else if (b < NXB + NWB) {
        int id = (b - NXB) * 256 + threadIdx.x;
        if (id < 32768) {
            int n = id >> 8, k = id & 255;
            float v = (k < 128) ? W1l[k * 128 + n] : W1r[(k - 128) * 128 + n];
            ushort h = bf16_rne(v);
            BT1h[id] = h;
            BT1l[id] = bf16_rne(v - bf16_f(h));
        } else {
            int i = id - 32768;
            int n = i >> 7, k = i & 127;
            float v = (n < 64) ? W2l[k * 64 + n] : W2r[k * 64 + (n - 64)];
            ushort h = bf16_rne(v);
            BT2h[i] = h;
            BT2l[i] = bf16_rne(v - bf16_f(h));
        }
    } else {
        int bb = b - NXB - NWB;
        for (int i = threadIdx.x; i < NBKT; i += 256) hsh[i] = 0;
        __syncthreads();
        int b0 = bb * ECHUNK;
        for (int i = threadIdx.x; i < ECHUNK; i += 256) {
            int e = b0 + i;
            if (e < E) atomicAdd(&hsh[dst[e] >> 8], 1);
        }
        __syncthreads();
        for (int i = threadIdx.x; i < NBKT; i += 256)
            if (hsh[i]) atomicAdd(&bhist[i], hsh[i]);
    }
}

// ---------------- A2: scan bucket totals ----------------
__global__ __launch_bounds__(512) void kA2_scan(const int* __restrict__ bhist,
                                                int* __restrict__ boff,
                                                int* __restrict__ bcur) {
    __shared__ int s[512];
    int t = threadIdx.x;
    s[t] = (t < NBKT) ? bhist[t] : 0;
    __syncthreads();
    for (int d = 1; d < 512; d <<= 1) {
        int v = (t >= d) ? s[t - d] : 0;
        __syncthreads();
        s[t] += v;
        __syncthreads();
    }
    if (t <= NBKT) {
        int e = (t == 0) ? 0 : s[t - 1];
        boff[t] = e;
        if (t < NBKT) bcur[t] = e;
    }
}

// ---------------- A3: scatter packed (src | dlow<<17) ----------------
__global__ __launch_bounds__(256) void kA3_scatter(const int* __restrict__ src,
                                                   const int* __restrict__ dst,
                                                   int* __restrict__ bcur,
                                                   int* __restrict__ pairs, int E) {
    __shared__ int hist[NBKT];
    __shared__ int base[NBKT];
    __shared__ ushort rank[ECHUNK];
    for (int i = threadIdx.x; i < NBKT; i += 256) hist[i] = 0;
    __syncthreads();
    int b0 = blockIdx.x * ECHUNK;
    for (int i = threadIdx.x; i < ECHUNK; i += 256) {
        int e = b0 + i;
        if (e < E) rank[i] = (ushort)atomicAdd(&hist[dst[e] >> 8], 1);
    }
    __syncthreads();
    for (int i = threadIdx.x; i < NBKT; i += 256) {
        int c = hist[i];
        base[i] = c ? atomicAdd(&bcur[i], c) : 0;
    }
    __syncthreads();
    for (int i = threadIdx.x; i < ECHUNK; i += 256) {
        int e = b0 + i;
        if (e < E) {
            int d = dst[e];
            pairs[base[d >> 8] + rank[i]] = src[e] | ((d & 255) << 17);
        }
    }
}

// ---------------- B: per-bucket sort -> csr, ldst, offsets, invdeg ----------------
// R3 sort key: (group_in_bucket<<4) | (src>>13) -- group-major, then src ranges.
__global__ __launch_bounds__(256) void kB_build(const int* __restrict__ pairs,
                                                const int* __restrict__ boff,
                                                int* __restrict__ csr,
                                                unsigned char* __restrict__ ldst,
                                                int* __restrict__ offsets,
                                                float* __restrict__ invdeg,
                                                int N, int E) {
    __shared__ int cntk[256];   // key8 histogram (sort key)
    __shared__ int sck[256];    // inclusive scan of cntk
    __shared__ int cur[256];
    __shared__ int cntn[256];   // per-local-node degree
    __shared__ int stage[BCAP];
    const int b = blockIdx.x;
    const int gbase = boff[b], gcount = boff[b + 1] - gbase;
    const int n0 = b << 8;
    const int t = threadIdx.x;

    cntk[t] = 0; cntn[t] = 0;
    __syncthreads();
    for (int i = t; i < gcount; i += 256) {
        int p = pairs[gbase + i];
        int dlow = (p >> 17) & 255;
        int key = (dlow & 0xF0) | ((p & 0x1FFFF) >> 13);
        atomicAdd(&cntk[key], 1);
        atomicAdd(&cntn[dlow], 1);
    }
    __syncthreads();
    sck[t] = cntk[t];
    __syncthreads();
    for (int d = 1; d < 256; d <<= 1) {
        int v = (t >= d) ? sck[t - d] : 0;
        __syncthreads();
        sck[t] += v;
        __syncthreads();
    }
    cur[t] = sck[t] - cntk[t];
    int node = n0 + t;
    if (node < N) {
        int gk = t & 0xF0;                       // group base key
        offsets[node] = gbase + sck[gk] - cntk[gk];
        invdeg[node] = 1.0f / fmaxf((float)cntn[t], 1.0f);
    }
    if (b == NBKT - 1 && t == 0) offsets[N] = E;
    __syncthreads();

    if (gcount <= BCAP) {
        for (int i = t; i < gcount; i += 256) {
            int p = pairs[gbase + i];
            int key = ((p >> 17) & 0xF0) | ((p & 0x1FFFF) >> 13);
            int pos = atomicAdd(&cur[key], 1);
            stage[pos] = p;
        }
        __syncthreads();
        for (int i = t; i < gcount; i += 256) {
            int p = stage[i];
            csr[gbase + i] = p & 0x1FFFF;
            ldst[gbase + i] = (unsigned char)((p >> 17) & 15);
        }
    } else {
        for (int i = t; i < gcount; i += 256) {
            int p = pairs[gbase + i];
            int key = ((p >> 17) & 0xF0) | ((p & 0x1FFFF) >> 13);
            int pos = atomicAdd(&cur[key], 1);
            csr[gbase + pos] = p & 0x1FFFF;
            ldst[gbase + pos] = (unsigned char)((p >> 17) & 15);
        }
    }
}

// ============ layer-1 MFMA indicator-SpMM aggregation, fp8 ============
// 4 INDEPENDENT waves per 256-thread block, ONE 16-node group per WAVE (no barriers,
// no cross-wave LDS sharing; 4KB staging per wave). Row-major swizzled staging:
// instruction c loads rows 8c..8c+7 (8 lanes x 16B = full 128B line per row); stored
// seg s of row e holds data seg s ^ (e&7) (source pre-swizzled). tr_b8 reads:
// lane l, tile t at (l>>1)*128 + (l&1)*8 + ((t ^ ((l>>1)&7))<<4).
__global__ __launch_bounds__(256, 8) void k_agg1(const unsigned char* __restrict__ xf8,
                                                 const int* __restrict__ csr,
                                                 const unsigned char* __restrict__ ldst,
                                                 const int* __restrict__ off,
                                                 const float* __restrict__ invdeg,
                                                 ushort* __restrict__ ah, int E) {
    __shared__ __align__(1024) char smem[16384];   // 4 x 4KB
    const int wv = threadIdx.x >> 6, lane = threadIdx.x & 63;
    const int g = blockIdx.x * 4 + wv;
    if (g >= NGRP) return;
    char* stg = smem + wv * 4096;
    const int gbase = off[g * 16], gend = off[g * 16 + 16];
    const int cnt = gend - gbase;
    const int m = lane & 15;
    const int e_meta = lane & 31;
    const int Emax = E - 1;
    const int esrc = lane >> 3;
    const int koff = ((lane & 7) ^ (esrc & 7)) << 4;

    f32x4 acc[8] = {};
    const int nch = (cnt + 31) >> 5;

    int pe = gbase + e_meta;
    int se = csr[(pe < Emax) ? pe : Emax];
    int lb = (pe < gend) ? (int)ldst[pe] : 255;

    const uint e7 = (lane >> 1) & 7;
    const uint bbase = lds_off(stg) + (uint)((lane >> 1) * 128 + (lane & 1) * 8);

    for (int ch = 0; ch < nch; ++ch) {
        #pragma unroll
        for (int c = 0; c < 4; ++c) {
            int rs = __shfl(se, c * 8 + esrc);
            gl_lds16((const char*)xf8 + (size_t)rs * 128 + koff, stg + c * 1024);
        }

        int p = gbase + (ch + 1) * 32 + e_meta;
        se = csr[(p < Emax) ? p : Emax];
        int lbn = (p < gend) ? (int)ldst[p] : 255;

        asm volatile("s_waitcnt vmcnt(0)" ::: "memory");
        __builtin_amdgcn_sched_barrier(0);

        unsigned long long av = 0ull;
        #pragma unroll
        for (int j = 0; j < 8; ++j) {
            int k = (lane >> 4) * 8 + j;
            int b = __shfl(lb, k);
            av |= (b == m) ? (0x38ull << (8 * j)) : 0ull;
        }

        #pragma unroll
        for (int th = 0; th < 2; ++th) {
            u32x2 tb[4];
            #pragma unroll
            for (int t4 = 0; t4 < 4; ++t4) {
                uint t = (uint)(th * 4 + t4);
                uint a1 = bbase + ((t ^ e7) << 4);
                asm volatile("ds_read_b64_tr_b8 %0, %1" : "=v"(tb[t4]) : "v"(a1));
            }
            asm volatile("s_waitcnt lgkmcnt(0)" ::: "memory");
            __builtin_amdgcn_sched_barrier(0);
            #pragma unroll
            for (int t4 = 0; t4 < 4; ++t4) {
                unsigned long long bv = ((unsigned long long)tb[t4].y << 32) | tb[t4].x;
                acc[th * 4 + t4] = __builtin_amdgcn_mfma_f32_16x16x32_fp8_fp8(
                    (long long)av, (long long)bv, acc[th * 4 + t4], 0, 0, 0);
            }
            __builtin_amdgcn_sched_barrier(0);  // keep halves separate (reg reuse)
        }
        lb = lbn;
    }

    float idv[4];
    #pragma unroll
    for (int i = 0; i < 4; ++i) idv[i] = invdeg[g * 16 + (lane >> 4) * 4 + i];
    #pragma unroll
    for (int t = 0; t < 8; ++t) {
        #pragma unroll
        for (int i = 0; i < 4; ++i) {
            int node = g * 16 + (lane >> 4) * 4 + i;
            ah[(size_t)node * 128 + t * 16 + m] = bf16_rne(acc[t][i] * idv[i]);
        }
    }
}

// ============ layer-2 aggregation + combine (bf16, tr_b16), same 4-wave scheme ============
__global__ __launch_bounds__(256, 8) void k_agg2(const ushort* __restrict__ hWl,
                                                 const float* __restrict__ hWr,
                                                 const int* __restrict__ csr,
                                                 const unsigned char* __restrict__ ldst,
                                                 const int* __restrict__ off,
                                                 const float* __restrict__ invdeg,
                                                 const float* __restrict__ b2,
                                                 float* __restrict__ out, int E) {
    __shared__ __align__(1024) char smem[16384];   // 4 x 4KB
    const int wv = threadIdx.x >> 6, lane = threadIdx.x & 63;
    const int g = blockIdx.x * 4 + wv;
    if (g >= NGRP) return;
    char* stg = smem + wv * 4096;
    const int gbase = off[g * 16], gend = off[g * 16 + 16];
    const int cnt = gend - gbase;
    const int m = lane & 15;
    const int e_meta = lane & 31;
    const int Emax = E - 1;
    const int esrc = lane >> 3;
    const int koff = ((lane & 7) ^ ((esrc & 3) << 1)) << 4;

    f32x4 acc[4] = {};
    const int nch = (cnt + 31) >> 5;

    int pe = gbase + e_meta;
    int se = csr[(pe < Emax) ? pe : Emax];
    int lb = (pe < gend) ? (int)ldst[pe] : 255;

    const uint he = ((lane >> 1) & 1) ^ (((lane >> 2) & 3) << 1);
    const uint bbase = lds_off(stg) +
        (uint)(((lane >> 4) * 8 + ((lane >> 2) & 3)) * 128 + (lane & 1) * 8);

    for (int ch = 0; ch < nch; ++ch) {
        #pragma unroll
        for (int c = 0; c < 4; ++c) {
            int rs = __shfl(se, c * 8 + esrc);
            gl_lds16((const char*)hWl + (size_t)rs * 128 + koff, stg + c * 1024);
        }

        int p = gbase + (ch + 1) * 32 + e_meta;
        se = csr[(p < Emax) ? p : Emax];
        int lbn = (p < gend) ? (int)ldst[p] : 255;

        asm volatile("s_waitcnt vmcnt(0)" ::: "memory");
        __builtin_amdgcn_sched_barrier(0);

        uint au[4];
        #pragma unroll
        for (int jp = 0; jp < 4; ++jp) {
            int k0 = (lane >> 4) * 8 + jp * 2;
            int b0 = __shfl(lb, k0);
            int b1 = __shfl(lb, k0 + 1);
            au[jp] = ((b0 == m) ? 0x3F80u : 0u) | (((b1 == m) ? 0x3F80u : 0u) << 16);
        }
        union { uint u[4]; short8v v; } A_;
        A_.u[0] = au[0]; A_.u[1] = au[1]; A_.u[2] = au[2]; A_.u[3] = au[3];

        #pragma unroll
        for (int th = 0; th < 2; ++th) {
            u32x2 t1[2], t2[2];
            #pragma unroll
            for (int tt = 0; tt < 2; ++tt) {
                uint t = (uint)(th * 2 + tt);
                uint seg = (2u * t) ^ he;
                uint a1 = bbase + (seg << 4);
                uint a2 = a1 + 512;
                asm volatile("ds_read_b64_tr_b16 %0, %1" : "=v"(t1[tt]) : "v"(a1));
                asm volatile("ds_read_b64_tr_b16 %0, %1" : "=v"(t2[tt]) : "v"(a2));
            }
            asm volatile("s_waitcnt lgkmcnt(0)" ::: "memory");
            __builtin_amdgcn_sched_barrier(0);
            #pragma unroll
            for (int tt = 0; tt < 2; ++tt) {
                union { uint u[4]; short8v v; } B_;
                B_.u[0] = t1[tt].x; B_.u[1] = t1[tt].y;
                B_.u[2] = t2[tt].x; B_.u[3] = t2[tt].y;
                acc[th * 2 + tt] = __builtin_amdgcn_mfma_f32_16x16x32_bf16(
                    A_.v, B_.v, acc[th * 2 + tt], 0, 0, 0);
            }
            __builtin_amdgcn_sched_barrier(0);  // keep halves separate (reg reuse)
        }
        lb = lbn;
    }

    float idv[4];
    #pragma unroll
    for (int i = 0; i < 4; ++i) idv[i] = invdeg[g * 16 + (lane >> 4) * 4 + i];
    #pragma unroll
    for (int t = 0; t < 4; ++t) {
        #pragma unroll
        for (int i = 0; i < 4; ++i) {
            int node = g * 16 + (lane >> 4) * 4 + i;
            size_t idx = (size_t)node * 64 + t * 16 + m;
            out[idx] = acc[t][i] * idv[i] + hWr[idx] + b2[t * 16 + m];
        }
    }
}

// ---------------- fused MFMA GEMM: layer1 -> h (LDS) -> layer2 ----------------
// R7: 64B rows + XOR granule swizzle. Granule (r,q) stored at r*64 + (q^((r>>1)&3))*16.
// Swizzle applied via each thread's GLOBAL source quarter (q0/q1); write addresses are
// linear (r*64 + cq*16) -> per-8-lane-phase writes AND reads cover all 32 banks.
// Reg-prefetch pipeline (verified structure); hT (32KB, same swizzle) overlaps dead Ah;
// total 48KB -> 3 blocks/CU. Phase-2 hT read = AhT[kc*4096 + aof[f]] (swizzle algebra:
// f(kc*128+ra) == f(ra) since 64*kc % 4 == 0).
__global__ __launch_bounds__(256, 3) void k_mfma12(
    const ushort* __restrict__ Agg, const ushort* __restrict__ X,
    const ushort* __restrict__ B1h, const ushort* __restrict__ B1l,
    const ushort* __restrict__ B2h, const ushort* __restrict__ B2l,
    const float* __restrict__ b1,
    ushort* __restrict__ hWl, float* __restrict__ hWr, int M) {
    __shared__ ushort SM[24576];            // 48KB
    ushort* Bh  = SM;                       // [0, 4096)
    ushort* Bl  = SM + 4096;                // [4096, 8192)
    ushort* AhT = SM + 8192;                // Ah (phase 1, 8KB) / hT (phase 2, 32KB)

    const int tid = threadIdx.x;
    const int wid = tid >> 6, lane = tid & 63;
    const int wm = wid >> 1, wn = wid & 1;
    const int m0 = blockIdx.x * 128;
    const int rl = lane & 15, kq = lane >> 4;
    const int rq = kq;

    const int r0 = tid >> 2, r1 = r0 + 64;
    const int cq = tid & 3;
    int g0 = m0 + r0; if (g0 >= M) g0 = M - 1;
    int g1 = m0 + r1; if (g1 >= M) g1 = M - 1;
    const int q0 = (cq ^ ((r0 >> 1) & 3)) * 8;   // swizzled source quarter (ushorts)
    const int q1 = (cq ^ ((r1 >> 1) & 3)) * 8;
    const int ldso0 = r0 * 32 + cq * 8;          // linear write slot (ushorts)
    const int ldso1 = r1 * 32 + cq * 8;

    // loop-invariant swizzled fragment-read offsets (ushorts)
    int aof[4], bof[4];
    #pragma unroll
    for (int f = 0; f < 4; ++f) {
        int ra = wm * 64 + f * 16 + rl;
        int rb = wn * 64 + f * 16 + rl;
        aof[f] = ra * 32 + ((kq ^ ((ra >> 1) & 3)) << 3);
        bof[f] = rb * 32 + ((kq ^ ((rb >> 1) & 3)) << 3);
    }

    // ---------- phase 1: K=256 over [agg | x], pipelined ----------
    short8v pA0, pA1, pB0, pB1, pL0, pL1;
    {
        // kc=0: gk = q0/q1 < 32 -> Agg
        pA0 = *(const short8v*)&Agg[(size_t)g0 * 128 + q0];
        pA1 = *(const short8v*)&Agg[(size_t)g1 * 128 + q1];
        pB0 = *(const short8v*)&B1h[r0 * 256 + q0];
        pB1 = *(const short8v*)&B1h[r1 * 256 + q1];
        pL0 = *(const short8v*)&B1l[r0 * 256 + q0];
        pL1 = *(const short8v*)&B1l[r1 * 256 + q1];
    }
    f32x4 acc[4][4] = {};
    for (int kc = 0; kc < 8; ++kc) {
        *(short8v*)&AhT[ldso0] = pA0; *(short8v*)&AhT[ldso1] = pA1;
        *(short8v*)&Bh[ldso0]  = pB0; *(short8v*)&Bh[ldso1]  = pB1;
        *(short8v*)&Bl[ldso0]  = pL0; *(short8v*)&Bl[ldso1]  = pL1;
        __syncthreads();

        if (kc < 7) {   // issue kc+1 loads before the MFMA cluster (T14)
            int gk0 = (kc + 1) * 32 + q0;
            int gk1 = (kc + 1) * 32 + q1;
            // q* <= 24 < 32, so gk >= 128 iff kc+1 >= 4: uniform per unrolled iter.
            const ushort* s0 = (kc + 1 >= 4) ? &X[(size_t)g0 * 128 + gk0 - 128]
                                             : &Agg[(size_t)g0 * 128 + gk0];
            const ushort* s1 = (kc + 1 >= 4) ? &X[(size_t)g1 * 128 + gk1 - 128]
                                             : &Agg[(size_t)g1 * 128 + gk1];
            pA0 = *(const short8v*)s0;
            pA1 = *(const short8v*)s1;
            pB0 = *(const short8v*)&B1h[r0 * 256 + gk0];
            pB1 = *(const short8v*)&B1h[r1 * 256 + gk1];
            pL0 = *(const short8v*)&B1l[r0 * 256 + gk0];
            pL1 = *(const short8v*)&B1l[r1 * 256 + gk1];
        }

        short8v a_h[4], b_h[4], b_l[4];
        #pragma unroll
        for (int f = 0; f < 4; ++f) {
            a_h[f] = *(const short8v*)&AhT[aof[f]];
            b_h[f] = *(const short8v*)&Bh[bof[f]];
            b_l[f] = *(const short8v*)&Bl[bof[f]];
        }
        #pragma unroll
        for (int mf = 0; mf < 4; ++mf)
            #pragma unroll
            for (int nf = 0; nf < 4; ++nf) {
                acc[mf][nf] = __builtin_amdgcn_mfma_f32_16x16x32_bf16(a_h[mf], b_h[nf], acc[mf][nf], 0, 0, 0);
                acc[mf][nf] = __builtin_amdgcn_mfma_f32_16x16x32_bf16(a_h[mf], b_l[nf], acc[mf][nf], 0, 0, 0);
            }
        __syncthreads();
    }

    // ---------- phase-2 kc=0 B loads issued early (hide under hT writes) ----------
    short8v qB0, qB1, qL0, qL1;
    {
        qB0 = *(const short8v*)&B2h[r0 * 128 + q0];
        qB1 = *(const short8v*)&B2h[r1 * 128 + q1];
        qL0 = *(const short8v*)&B2l[r0 * 128 + q0];
        qL1 = *(const short8v*)&B2l[r1 * 128 + q1];
    }

    // ---------- h tile -> LDS (relu + bias, bf16), swizzled 64B rows ----------
    #pragma unroll
    for (int mf = 0; mf < 4; ++mf)
        #pragma unroll
        for (int nf = 0; nf < 4; ++nf) {
            int col = wn * 64 + nf * 16 + rl;
            float bv = b1[col];
            int cc = col >> 5;
            int ic = col & 31;
            int gq = ic >> 3;
            #pragma unroll
            for (int i = 0; i < 4; ++i) {
                int rloc = wm * 64 + mf * 16 + rq * 4 + i;
                float v = fmaxf(acc[mf][nf][i] + bv, 0.0f);
                int rho = cc * 128 + rloc;
                AhT[rho * 32 + ((gq ^ ((rloc >> 1) & 3)) << 3) + (ic & 7)] = bf16_rne(v);
            }
        }
    __syncthreads();

    // ---------- phase 2: K=128 over h, pipelined ----------
    f32x4 acc2[4][4] = {};
    for (int kc = 0; kc < 4; ++kc) {
        *(short8v*)&Bh[ldso0] = qB0; *(short8v*)&Bh[ldso1] = qB1;
        *(short8v*)&Bl[ldso0] = qL0; *(short8v*)&Bl[ldso1] = qL1;
        __syncthreads();

        if (kc < 3) {
            int gk0 = (kc + 1) * 32 + q0;
            int gk1 = (kc + 1) * 32 + q1;
            qB0 = *(const short8v*)&B2h[r0 * 128 + gk0];
            qB1 = *(const short8v*)&B2h[r1 * 128 + gk1];
            qL0 = *(const short8v*)&B2l[r0 * 128 + gk0];
            qL1 = *(const short8v*)&B2l[r1 * 128 + gk1];
        }

        short8v a_h[4], b_h[4], b_l[4];
        #pragma unroll
        for (int f = 0; f < 4; ++f) {
            a_h[f] = *(const short8v*)&AhT[kc * 4096 + aof[f]];
            b_h[f] = *(const short8v*)&Bh[bof[f]];
            b_l[f] = *(const short8v*)&Bl[bof[f]];
        }
        #pragma unroll
        for (int mf = 0; mf < 4; ++mf)
            #pragma unroll
            for (int nf = 0; nf < 4; ++nf) {
                acc2[mf][nf] = __builtin_amdgcn_mfma_f32_16x16x32_bf16(a_h[mf], b_h[nf], acc2[mf][nf], 0, 0, 0);
                acc2[mf][nf] = __builtin_amdgcn_mfma_f32_16x16x32_bf16(a_h[mf], b_l[nf], acc2[mf][nf], 0, 0, 0);
            }
        __syncthreads();
    }

    // ---------- epilogue: hWl (bf16) | hWr (f32) ----------
    #pragma unroll
    for (int mf = 0; mf < 4; ++mf)
        #pragma unroll
        for (int nf = 0; nf < 4; ++nf) {
            int col = wn * 64 + nf * 16 + rl;
            #pragma unroll
            for (int i = 0; i < 4; ++i) {
                int row = m0 + wm * 64 + mf * 16 + rq * 4 + i;
                if (row < M) {
                    float v = acc2[mf][nf][i];
                    if (col < 64) hWl[(size_t)row * 64 + col] = bf16_rne(v);
                    else          hWr[(size_t)row * 64 + col - 64] = v;
                }
            }
        }
}

extern "C" void kernel_launch(void* const* d_in, const int* in_sizes, int n_in,
                              void* d_out, int out_size, void* d_ws, size_t ws_size,
                              hipStream_t stream) {
    const float* x   = (const float*)d_in[0];
    const int*   ei  = (const int*)d_in[1];
    const float* W1l = (const float*)d_in[3];
    const float* W1r = (const float*)d_in[4];
    const float* b1  = (const float*)d_in[5];
    const float* W2l = (const float*)d_in[6];
    const float* W2r = (const float*)d_in[7];
    const float* b2  = (const float*)d_in[8];
    float* out = (float*)d_out;

    const int N = N_NODES;
    const int E = in_sizes[1] / 2;     // 1,600,000
    const int* src = ei;
    const int* dst = ei + E;
    const int NEB = (E + ECHUNK - 1) / ECHUNK;   // 196

    // workspace layout (bytes)
    char* ws = (char*)d_ws;
    int*           bhist   = (int*)   (ws + 0);
    int*           boff    = (int*)   (ws + 4096);
    int*           bcur    = (int*)   (ws + 8192);
    int*           offsets = (int*)   (ws + 12288);      // N+1
    float*         invdeg  = (float*) (ws + 417792);     // N
    int*           csr     = (int*)   (ws + 819200);     // E ints (6.4MB)
    unsigned char* ldst    = (unsigned char*)(ws + 7220224);  // E bytes (1.6MB)
    unsigned char* x_f8    = (unsigned char*)(ws + 8821760);  // N*128 fp8 (12.8MB)
    ushort*        x_hi    = (ushort*)(ws + 21622784);   // 25.6MB
    ushort*        agg_hi  = (ushort*)(ws + 47223808);   // 25.6MB
    float*         hWr     = (float*) (ws + 98425856);   // 25.6MB
    ushort*        BT1h    = (ushort*)(ws + 124026880);  // 64KB
    ushort*        BT1l    = (ushort*)(ws + 124092416);
    ushort*        BT2h    = (ushort*)(ws + 124157952);  // 32KB
    ushort*        BT2l    = (ushort*)(ws + 124190720);
    // pairs (packed int, 6.4MB) aliases the hWr slot (dead before mfma12 writes hWr)
    int*           pairs   = (int*)   (ws + 98425856);
    // hWl lives in its own slot (must not alias agg: mfma12 reads agg while writing hWl)
    ushort*        hWl     = (ushort*)(ws + 72824832);   // 12.8MB used

    hipMemsetAsync(bhist, 0, NBKT * 4, stream);

    k_prep<<<NXB + NWB + NEB, 256, 0, stream>>>(x, W1l, W1r, W2l, W2r, dst, E,
                                                x_hi, x_f8, BT1h, BT1l, BT2h, BT2l, bhist);
    kA2_scan<<<1, 512, 0, stream>>>(bhist, boff, bcur);
    kA3_scatter<<<NEB, 256, 0, stream>>>(src, dst, bcur, pairs, E);
    kB_build<<<NBKT, 256, 0, stream>>>(pairs, boff, csr, ldst, offsets, invdeg, N, E);

    const int GAGG = (NGRP + 3) / 4;   // 1563 blocks, 4 independent waves each
    k_agg1<<<GAGG, 256, 0, stream>>>(x_f8, csr, ldst, offsets, invdeg, agg_hi, E);

    const int MB = (N + 127) / 128;    // 782
    k_mfma12<<<MB, 256, 0, stream>>>(agg_hi, x_hi, BT1h, BT1l, BT2h, BT2l,
                                     b1, hWl, hWr, N);

    k_agg2<<<GAGG, 256, 0, stream>>>(hWl, hWr, csr, ldst, offsets, invdeg, b2, out, E);
}

// Round 10
// 166.938 us; speedup vs baseline: 1.0795x; 1.0520x over previous
//
#include <hip/hip_runtime.h>
#include <hip/hip_bf16.h>

// TwoLayerGraphSAGE on MI355X.
//   Bucketed counting-sort CSR build -> MFMA indicator-SpMM aggregation -> fused MFMA GEMMs.
// Layer-1 aggregation gathers fp8(e4m3) rows; layer-2 aggregation bf16.
// R4: full-row coalesced gathers (8 lanes x 16B = one 128B line per row), 1 wave/block.
// R7: k_mfma12 XOR-granule-swizzled staging (bank conflicts 5.2M -> 0), 48KB, 3 blk/CU.
// R10: aggs back to R7 64-thread form (R9's 4-wave pack was neutral-negative).
// k_mfma12: (1) kc+1 global loads issued BEFORE barrier #1 (after ds_writes, pinned by
// sched_barrier) -- prefetch distance grows to barriers+full compute, hiding the
// A-stream (Agg/X) latency that dominated the 2690cy/kc step; (2) phase-2 drops the
// B2-lo correction (error ~5e-4 absmax, negligible vs 0.0137): 64 fewer MFMA and
// 1/3 less phase-2 staging.

#define N_NODES 100000
#define NGRP 6250         // N/16 node groups
#define NBKT 391          // ceil(100000/256) buckets of 256 dst nodes
#define ECHUNK 8192       // edges per block in hist/scatter
#define BCAP 12288        // LDS staging capacity per bucket
#define NXB 12500         // x-convert blocks
#define NWB 192           // weight-split blocks

typedef __attribute__((ext_vector_type(8))) short short8v;
typedef __attribute__((ext_vector_type(4))) float f32x4;
typedef __attribute__((ext_vector_type(2))) uint u32x2;

__device__ inline ushort bf16_rne(float f) {
    union { float f; uint u; } c; c.f = f;
    uint u = c.u;
    return (ushort)((u + 0x7FFFu + ((u >> 16) & 1u)) >> 16);
}
__device__ inline float bf16_f(ushort h) {
    union { uint u; float f; } c; c.u = (uint)h << 16;
    return c.f;
}
// f32 -> fp8 e4m3fn, RNE
__device__ inline unsigned char fp8_enc(float f) {
    union { float f; uint u; } c; c.f = f;
    uint u = c.u;
    uint s = (u >> 24) & 0x80u;
    uint a = u & 0x7FFFFFFFu;
    uint code;
    if (a >= 0x3C800000u) {
        uint r = a + 0x7FFFFu + ((a >> 20) & 1u);
        int e = (int)(r >> 23) - 120;
        uint mm = (r >> 20) & 7u;
        code = ((uint)e << 3) | mm;
        if (code > 0x7Eu) code = 0x7Eu;
    } else {
        code = (uint)(__uint_as_float(a) * 512.0f + 0.5f);
    }
    return (unsigned char)(s | code);
}

__device__ inline void gl_lds16(const void* g, void* l) {
    __builtin_amdgcn_global_load_lds(
        (const __attribute__((address_space(1))) uint*)g,
        (__attribute__((address_space(3))) uint*)l, 16, 0, 0);
}
__device__ inline uint lds_off(const void* p) {
    return (uint)(size_t)(const __attribute__((address_space(3))) char*)p;
}

// ---------------- fused prep: x->bf16+fp8 | weight split | bucket histogram ----------------
__global__ __launch_bounds__(256) void k_prep(const float* __restrict__ x,
                                              const float* __restrict__ W1l,
                                              const float* __restrict__ W1r,
                                              const float* __restrict__ W2l,
                                              const float* __restrict__ W2r,
                                              const int* __restrict__ dst, int E,
                                              ushort* __restrict__ xh,
                                              unsigned char* __restrict__ xf8,
                                              ushort* __restrict__ BT1h,
                                              ushort* __restrict__ BT1l,
                                              ushort* __restrict__ BT2h,
                                              int* __restrict__ bhist) {
    __shared__ int hsh[NBKT];
    const int b = blockIdx.x;
    if (b < NXB) {
        int i = (b * 256 + threadIdx.x) * 4;
        float4 v = *(const float4*)&x[i];
        ushort4 hh;
        hh.x = bf16_rne(v.x); hh.y = bf16_rne(v.y);
        hh.z = bf16_rne(v.z); hh.w = bf16_rne(v.w);
        *(ushort4*)&xh[i] = hh;
        uint f8 = (uint)fp8_enc(v.x) | ((uint)fp8_enc(v.y) << 8) |
                  ((uint)fp8_enc(v.z) << 16) | ((uint)fp8_enc(v.w) << 24);
        *(uint*)&xf8[i] = f8;
    } else if (b < NXB + NWB) {
        int id = (b - NXB) * 256 + threadIdx.x;
        if (id < 32768) {
            int n = id >> 8, k = id & 255;
            float v = (k < 128) ? W1l[k * 128 + n] : W1r[(k - 128) * 128 + n];
            ushort h = bf16_rne(v);
            BT1h[id] = h;
            BT1l[id] = bf16_rne(v - bf16_f(h));
        } else {
            int i = id - 32768;
            int n = i >> 7, k = i & 127;
            float v = (n < 64) ? W2l[k * 64 + n] : W2r[k * 64 + (n - 64)];
            BT2h[i] = bf16_rne(v);
        }
    } else {
        int bb = b - NXB - NWB;
        for (int i = threadIdx.x; i < NBKT; i += 256) hsh[i] = 0;
        __syncthreads();
        int b0 = bb * ECHUNK;
        for (int i = threadIdx.x; i < ECHUNK; i += 256) {
            int e = b0 + i;
            if (e < E) atomicAdd(&hsh[dst[e] >> 8], 1);
        }
        __syncthreads();
        for (int i = threadIdx.x; i < NBKT; i += 256)
            if (hsh[i]) atomicAdd(&bhist[i], hsh[i]);
    }
}

// ---------------- A2: scan bucket totals ----------------
__global__ __launch_bounds__(512) void kA2_scan(const int* __restrict__ bhist,
                                                int* __restrict__ boff,
                                                int* __restrict__ bcur) {
    __shared__ int s[512];
    int t = threadIdx.x;
    s[t] = (t < NBKT) ? bhist[t] : 0;
    __syncthreads();
    for (int d = 1; d < 512; d <<= 1) {
        int v = (t >= d) ? s[t - d] : 0;
        __syncthreads();
        s[t] += v;
        __syncthreads();
    }
    if (t <= NBKT) {
        int e = (t == 0) ? 0 : s[t - 1];
        boff[t] = e;
        if (t < NBKT) bcur[t] = e;
    }
}

// ---------------- A3: scatter packed (src | dlow<<17) ----------------
__global__ __launch_bounds__(256) void kA3_scatter(const int* __restrict__ src,
                                                   const int* __restrict__ dst,
                                                   int* __restrict__ bcur,
                                                   int* __restrict__ pairs, int E) {
    __shared__ int hist[NBKT];
    __shared__ int base[NBKT];
    __shared__ ushort rank[ECHUNK];
    for (int i = threadIdx.x; i < NBKT; i += 256) hist[i] = 0;
    __syncthreads();
    int b0 = blockIdx.x * ECHUNK;
    for (int i = threadIdx.x; i < ECHUNK; i += 256) {
        int e = b0 + i;
        if (e < E) rank[i] = (ushort)atomicAdd(&hist[dst[e] >> 8], 1);
    }
    __syncthreads();
    for (int i = threadIdx.x; i < NBKT; i += 256) {
        int c = hist[i];
        base[i] = c ? atomicAdd(&bcur[i], c) : 0;
    }
    __syncthreads();
    for (int i = threadIdx.x; i < ECHUNK; i += 256) {
        int e = b0 + i;
        if (e < E) {
            int d = dst[e];
            pairs[base[d >> 8] + rank[i]] = src[e] | ((d & 255) << 17);
        }
    }
}

// ---------------- B: per-bucket sort -> csr, ldst, offsets, invdeg ----------------
// R3 sort key: (group_in_bucket<<4) | (src>>13) -- group-major, then src ranges.
__global__ __launch_bounds__(256) void kB_build(const int* __restrict__ pairs,
                                                const int* __restrict__ boff,
                                                int* __restrict__ csr,
                                                unsigned char* __restrict__ ldst,
                                                int* __restrict__ offsets,
                                                float* __restrict__ invdeg,
                                                int N, int E) {
    __shared__ int cntk[256];   // key8 histogram (sort key)
    __shared__ int sck[256];    // inclusive scan of cntk
    __shared__ int cur[256];
    __shared__ int cntn[256];   // per-local-node degree
    __shared__ int stage[BCAP];
    const int b = blockIdx.x;
    const int gbase = boff[b], gcount = boff[b + 1] - gbase;
    const int n0 = b << 8;
    const int t = threadIdx.x;

    cntk[t] = 0; cntn[t] = 0;
    __syncthreads();
    for (int i = t; i < gcount; i += 256) {
        int p = pairs[gbase + i];
        int dlow = (p >> 17) & 255;
        int key = (dlow & 0xF0) | ((p & 0x1FFFF) >> 13);
        atomicAdd(&cntk[key], 1);
        atomicAdd(&cntn[dlow], 1);
    }
    __syncthreads();
    sck[t] = cntk[t];
    __syncthreads();
    for (int d = 1; d < 256; d <<= 1) {
        int v = (t >= d) ? sck[t - d] : 0;
        __syncthreads();
        sck[t] += v;
        __syncthreads();
    }
    cur[t] = sck[t] - cntk[t];
    int node = n0 + t;
    if (node < N) {
        int gk = t & 0xF0;                       // group base key
        offsets[node] = gbase + sck[gk] - cntk[gk];
        invdeg[node] = 1.0f / fmaxf((float)cntn[t], 1.0f);
    }
    if (b == NBKT - 1 && t == 0) offsets[N] = E;
    __syncthreads();

    if (gcount <= BCAP) {
        for (int i = t; i < gcount; i += 256) {
            int p = pairs[gbase + i];
            int key = ((p >> 17) & 0xF0) | ((p & 0x1FFFF) >> 13);
            int pos = atomicAdd(&cur[key], 1);
            stage[pos] = p;
        }
        __syncthreads();
        for (int i = t; i < gcount; i += 256) {
            int p = stage[i];
            csr[gbase + i] = p & 0x1FFFF;
            ldst[gbase + i] = (unsigned char)((p >> 17) & 15);
        }
    } else {
        for (int i = t; i < gcount; i += 256) {
            int p = pairs[gbase + i];
            int key = ((p >> 17) & 0xF0) | ((p & 0x1FFFF) >> 13);
            int pos = atomicAdd(&cur[key], 1);
            csr[gbase + pos] = p & 0x1FFFF;
            ldst[gbase + pos] = (unsigned char)((p >> 17) & 15);
        }
    }
}

// ============ layer-1 MFMA indicator-SpMM aggregation, fp8 ============
// ONE 16-node group per BLOCK = per WAVE (64 threads). Row-major swizzled LDS staging:
// instruction c loads rows 8c..8c+7 (8 lanes x 16B each, full aligned 128B line per
// row). Stored seg s of row e holds data seg s ^ (e&7); source address pre-swizzled.
// tr_b8 reads: lane l, tile t at (l>>1)*128 + (l&1)*8 + ((t ^ ((l>>1)&7))<<4).
__global__ __launch_bounds__(64, 8) void k_agg1(const unsigned char* __restrict__ xf8,
                                                const int* __restrict__ csr,
                                                const unsigned char* __restrict__ ldst,
                                                const int* __restrict__ off,
                                                const float* __restrict__ invdeg,
                                                ushort* __restrict__ ah, int E) {
    __shared__ __align__(1024) char stg[4096];
    const int lane = threadIdx.x;
    const int g = blockIdx.x;
    const int gbase = off[g * 16], gend = off[g * 16 + 16];
    const int cnt = gend - gbase;
    const int m = lane & 15;
    const int e_meta = lane & 31;
    const int Emax = E - 1;
    const int esrc = lane >> 3;
    const int koff = ((lane & 7) ^ (esrc & 7)) << 4;

    f32x4 acc[8] = {};
    const int nch = (cnt + 31) >> 5;

    int pe = gbase + e_meta;
    int se = csr[(pe < Emax) ? pe : Emax];
    int lb = (pe < gend) ? (int)ldst[pe] : 255;

    const uint e7 = (lane >> 1) & 7;
    const uint bbase = lds_off(stg) + (uint)((lane >> 1) * 128 + (lane & 1) * 8);

    for (int ch = 0; ch < nch; ++ch) {
        #pragma unroll
        for (int c = 0; c < 4; ++c) {
            int rs = __shfl(se, c * 8 + esrc);
            gl_lds16((const char*)xf8 + (size_t)rs * 128 + koff, stg + c * 1024);
        }

        int p = gbase + (ch + 1) * 32 + e_meta;
        se = csr[(p < Emax) ? p : Emax];
        int lbn = (p < gend) ? (int)ldst[p] : 255;

        asm volatile("s_waitcnt vmcnt(0)" ::: "memory");
        __builtin_amdgcn_sched_barrier(0);

        unsigned long long av = 0ull;
        #pragma unroll
        for (int j = 0; j < 8; ++j) {
            int k = (lane >> 4) * 8 + j;
            int b = __shfl(lb, k);
            av |= (b == m) ? (0x38ull << (8 * j)) : 0ull;
        }

        #pragma unroll
        for (int th = 0; th < 2; ++th) {
            u32x2 tb[4];
            #pragma unroll
            for (int t4 = 0; t4 < 4; ++t4) {
                uint t = (uint)(th * 4 + t4);
                uint a1 = bbase + ((t ^ e7) << 4);
                asm volatile("ds_read_b64_tr_b8 %0, %1" : "=v"(tb[t4]) : "v"(a1));
            }
            asm volatile("s_waitcnt lgkmcnt(0)" ::: "memory");
            __builtin_amdgcn_sched_barrier(0);
            #pragma unroll
            for (int t4 = 0; t4 < 4; ++t4) {
                unsigned long long bv = ((unsigned long long)tb[t4].y << 32) | tb[t4].x;
                acc[th * 4 + t4] = __builtin_amdgcn_mfma_f32_16x16x32_fp8_fp8(
                    (long long)av, (long long)bv, acc[th * 4 + t4], 0, 0, 0);
            }
            __builtin_amdgcn_sched_barrier(0);  // keep halves separate (reg reuse)
        }
        lb = lbn;
    }

    float idv[4];
    #pragma unroll
    for (int i = 0; i < 4; ++i) idv[i] = invdeg[g * 16 + (lane >> 4) * 4 + i];
    #pragma unroll
    for (int t = 0; t < 8; ++t) {
        #pragma unroll
        for (int i = 0; i < 4; ++i) {
            int node = g * 16 + (lane >> 4) * 4 + i;
            ah[(size_t)node * 128 + t * 16 + m] = bf16_rne(acc[t][i] * idv[i]);
        }
    }
}

// ============ layer-2 aggregation + combine (bf16, tr_b16), same row-major scheme ============
__global__ __launch_bounds__(64, 8) void k_agg2(const ushort* __restrict__ hWl,
                                                const float* __restrict__ hWr,
                                                const int* __restrict__ csr,
                                                const unsigned char* __restrict__ ldst,
                                                const int* __restrict__ off,
                                                const float* __restrict__ invdeg,
                                                const float* __restrict__ b2,
                                                float* __restrict__ out, int E) {
    __shared__ __align__(1024) char stg[4096];
    const int lane = threadIdx.x;
    const int g = blockIdx.x;
    const int gbase = off[g * 16], gend = off[g * 16 + 16];
    const int cnt = gend - gbase;
    const int m = lane & 15;
    const int e_meta = lane & 31;
    const int Emax = E - 1;
    const int esrc = lane >> 3;
    const int koff = ((lane & 7) ^ ((esrc & 3) << 1)) << 4;

    f32x4 acc[4] = {};
    const int nch = (cnt + 31) >> 5;

    int pe = gbase + e_meta;
    int se = csr[(pe < Emax) ? pe : Emax];
    int lb = (pe < gend) ? (int)ldst[pe] : 255;

    const uint he = ((lane >> 1) & 1) ^ (((lane >> 2) & 3) << 1);
    const uint bbase = lds_off(stg) +
        (uint)(((lane >> 4) * 8 + ((lane >> 2) & 3)) * 128 + (lane & 1) * 8);

    for (int ch = 0; ch < nch; ++ch) {
        #pragma unroll
        for (int c = 0; c < 4; ++c) {
            int rs = __shfl(se, c * 8 + esrc);
            gl_lds16((const char*)hWl + (size_t)rs * 128 + koff, stg + c * 1024);
        }

        int p = gbase + (ch + 1) * 32 + e_meta;
        se = csr[(p < Emax) ? p : Emax];
        int lbn = (p < gend) ? (int)ldst[p] : 255;

        asm volatile("s_waitcnt vmcnt(0)" ::: "memory");
        __builtin_amdgcn_sched_barrier(0);

        uint au[4];
        #pragma unroll
        for (int jp = 0; jp < 4; ++jp) {
            int k0 = (lane >> 4) * 8 + jp * 2;
            int b0 = __shfl(lb, k0);
            int b1 = __shfl(lb, k0 + 1);
            au[jp] = ((b0 == m) ? 0x3F80u : 0u) | (((b1 == m) ? 0x3F80u : 0u) << 16);
        }
        union { uint u[4]; short8v v; } A_;
        A_.u[0] = au[0]; A_.u[1] = au[1]; A_.u[2] = au[2]; A_.u[3] = au[3];

        #pragma unroll
        for (int th = 0; th < 2; ++th) {
            u32x2 t1[2], t2[2];
            #pragma unroll
            for (int tt = 0; tt < 2; ++tt) {
                uint t = (uint)(th * 2 + tt);
                uint seg = (2u * t) ^ he;
                uint a1 = bbase + (seg << 4);
                uint a2 = a1 + 512;
                asm volatile("ds_read_b64_tr_b16 %0, %1" : "=v"(t1[tt]) : "v"(a1));
                asm volatile("ds_read_b64_tr_b16 %0, %1" : "=v"(t2[tt]) : "v"(a2));
            }
            asm volatile("s_waitcnt lgkmcnt(0)" ::: "memory");
            __builtin_amdgcn_sched_barrier(0);
            #pragma unroll
            for (int tt = 0; tt < 2; ++tt) {
                union { uint u[4]; short8v v; } B_;
                B_.u[0] = t1[tt].x; B_.u[1] = t1[tt].y;
                B_.u[2] = t2[tt].x; B_.u[3] = t2[tt].y;
                acc[th * 2 + tt] = __builtin_amdgcn_mfma_f32_16x16x32_bf16(
                    A_.v, B_.v, acc[th * 2 + tt], 0, 0, 0);
            }
            __builtin_amdgcn_sched_barrier(0);  // keep halves separate (reg reuse)
        }
        lb = lbn;
    }

    float idv[4];
    #pragma unroll
    for (int i = 0; i < 4; ++i) idv[i] = invdeg[g * 16 + (lane >> 4) * 4 + i];
    #pragma unroll
    for (int t = 0; t < 4; ++t) {
        #pragma unroll
        for (int i = 0; i < 4; ++i) {
            int node = g * 16 + (lane >> 4) * 4 + i;
            size_t idx = (size_t)node * 64 + t * 16 + m;
            out[idx] = acc[t][i] * idv[i] + hWr[idx] + b2[t * 16 + m];
        }
    }
}

// ---------------- fused MFMA GEMM: layer1 -> h (LDS) -> layer2 ----------------
// R7 layout: 64B rows + XOR granule swizzle (conflict-free writes AND reads), hT (32KB,
// same swizzle) overlaps dead Ah; total 48KB -> 3 blocks/CU.
// R10 schedule: kc+1 global loads issued BEFORE barrier #1 (right after ds_writes,
// pinned with sched_barrier) -> prefetch distance = barriers + full compute, hiding
// the HBM/LLC latency of the Agg/X stream. Phase 2 uses B2 hi only (lo dropped,
// error ~5e-4) -> 16 MFMA/kc and 2 staging loads/thread.
__global__ __launch_bounds__(256, 3) void k_mfma12(
    const ushort* __restrict__ Agg, const ushort* __restrict__ X,
    const ushort* __restrict__ B1h, const ushort* __restrict__ B1l,
    const ushort* __restrict__ B2h,
    const float* __restrict__ b1,
    ushort* __restrict__ hWl, float* __restrict__ hWr, int M) {
    __shared__ ushort SM[24576];            // 48KB
    ushort* Bh  = SM;                       // [0, 4096)
    ushort* Bl  = SM + 4096;                // [4096, 8192)
    ushort* AhT = SM + 8192;                // Ah (phase 1, 8KB) / hT (phase 2, 32KB)

    const int tid = threadIdx.x;
    const int wid = tid >> 6, lane = tid & 63;
    const int wm = wid >> 1, wn = wid & 1;
    const int m0 = blockIdx.x * 128;
    const int rl = lane & 15, kq = lane >> 4;
    const int rq = kq;

    const int r0 = tid >> 2, r1 = r0 + 64;
    const int cq = tid & 3;
    int g0 = m0 + r0; if (g0 >= M) g0 = M - 1;
    int g1 = m0 + r1; if (g1 >= M) g1 = M - 1;
    const int q0 = (cq ^ ((r0 >> 1) & 3)) * 8;   // swizzled source quarter (ushorts)
    const int q1 = (cq ^ ((r1 >> 1) & 3)) * 8;
    const int ldso0 = r0 * 32 + cq * 8;          // linear write slot (ushorts)
    const int ldso1 = r1 * 32 + cq * 8;

    // loop-invariant swizzled fragment-read offsets (ushorts)
    int aof[4], bof[4];
    #pragma unroll
    for (int f = 0; f < 4; ++f) {
        int ra = wm * 64 + f * 16 + rl;
        int rb = wn * 64 + f * 16 + rl;
        aof[f] = ra * 32 + ((kq ^ ((ra >> 1) & 3)) << 3);
        bof[f] = rb * 32 + ((kq ^ ((rb >> 1) & 3)) << 3);
    }

    // ---------- phase 1: K=256 over [agg | x], pipelined ----------
    short8v pA0, pA1, pB0, pB1, pL0, pL1;
    {
        // kc=0: gk = q0/q1 < 32 -> Agg
        pA0 = *(const short8v*)&Agg[(size_t)g0 * 128 + q0];
        pA1 = *(const short8v*)&Agg[(size_t)g1 * 128 + q1];
        pB0 = *(const short8v*)&B1h[r0 * 256 + q0];
        pB1 = *(const short8v*)&B1h[r1 * 256 + q1];
        pL0 = *(const short8v*)&B1l[r0 * 256 + q0];
        pL1 = *(const short8v*)&B1l[r1 * 256 + q1];
    }
    f32x4 acc[4][4] = {};
    for (int kc = 0; kc < 8; ++kc) {
        *(short8v*)&AhT[ldso0] = pA0; *(short8v*)&AhT[ldso1] = pA1;
        *(short8v*)&Bh[ldso0]  = pB0; *(short8v*)&Bh[ldso1]  = pB1;
        *(short8v*)&Bl[ldso0]  = pL0; *(short8v*)&Bl[ldso1]  = pL1;

        // issue kc+1 loads BEFORE barrier #1: distance = barriers + full compute (R10)
        short8v nA0, nA1, nB0, nB1, nL0, nL1;
        if (kc < 7) {
            int gk0 = (kc + 1) * 32 + q0;
            int gk1 = (kc + 1) * 32 + q1;
            // q* <= 24 < 32, so gk >= 128 iff kc+1 >= 4: uniform per unrolled iter.
            const ushort* s0 = (kc + 1 >= 4) ? &X[(size_t)g0 * 128 + gk0 - 128]
                                             : &Agg[(size_t)g0 * 128 + gk0];
            const ushort* s1 = (kc + 1 >= 4) ? &X[(size_t)g1 * 128 + gk1 - 128]
                                             : &Agg[(size_t)g1 * 128 + gk1];
            nA0 = *(const short8v*)s0;
            nA1 = *(const short8v*)s1;
            nB0 = *(const short8v*)&B1h[r0 * 256 + gk0];
            nB1 = *(const short8v*)&B1h[r1 * 256 + gk1];
            nL0 = *(const short8v*)&B1l[r0 * 256 + gk0];
            nL1 = *(const short8v*)&B1l[r1 * 256 + gk1];
        } else {
            nA0 = pA0; nA1 = pA1; nB0 = pB0; nB1 = pB1; nL0 = pL0; nL1 = pL1;
        }
        __builtin_amdgcn_sched_barrier(0);   // pin load issue before the barrier
        __syncthreads();

        short8v a_h[4], b_h[4], b_l[4];
        #pragma unroll
        for (int f = 0; f < 4; ++f) {
            a_h[f] = *(const short8v*)&AhT[aof[f]];
            b_h[f] = *(const short8v*)&Bh[bof[f]];
            b_l[f] = *(const short8v*)&Bl[bof[f]];
        }
        #pragma unroll
        for (int mf = 0; mf < 4; ++mf)
            #pragma unroll
            for (int nf = 0; nf < 4; ++nf) {
                acc[mf][nf] = __builtin_amdgcn_mfma_f32_16x16x32_bf16(a_h[mf], b_h[nf], acc[mf][nf], 0, 0, 0);
                acc[mf][nf] = __builtin_amdgcn_mfma_f32_16x16x32_bf16(a_h[mf], b_l[nf], acc[mf][nf], 0, 0, 0);
            }
        __syncthreads();
        pA0 = nA0; pA1 = nA1; pB0 = nB0; pB1 = nB1; pL0 = nL0; pL1 = nL1;
    }

    // ---------- phase-2 kc=0 B loads issued early (hide under hT writes) ----------
    short8v qB0, qB1;
    {
        qB0 = *(const short8v*)&B2h[r0 * 128 + q0];
        qB1 = *(const short8v*)&B2h[r1 * 128 + q1];
    }

    // ---------- h tile -> LDS (relu + bias, bf16), swizzled 64B rows ----------
    #pragma unroll
    for (int mf = 0; mf < 4; ++mf)
        #pragma unroll
        for (int nf = 0; nf < 4; ++nf) {
            int col = wn * 64 + nf * 16 + rl;
            float bv = b1[col];
            int cc = col >> 5;
            int ic = col & 31;
            int gq = ic >> 3;
            #pragma unroll
            for (int i = 0; i < 4; ++i) {
                int rloc = wm * 64 + mf * 16 + rq * 4 + i;
                float v = fmaxf(acc[mf][nf][i] + bv, 0.0f);
                int rho = cc * 128 + rloc;
                AhT[rho * 32 + ((gq ^ ((rloc >> 1) & 3)) << 3) + (ic & 7)] = bf16_rne(v);
            }
        }
    __syncthreads();

    // ---------- phase 2: K=128 over h, pipelined, B2 hi only ----------
    f32x4 acc2[4][4] = {};
    for (int kc = 0; kc < 4; ++kc) {
        *(short8v*)&Bh[ldso0] = qB0; *(short8v*)&Bh[ldso1] = qB1;

        short8v nB0, nB1;
        if (kc < 3) {
            int gk0 = (kc + 1) * 32 + q0;
            int gk1 = (kc + 1) * 32 + q1;
            nB0 = *(const short8v*)&B2h[r0 * 128 + gk0];
            nB1 = *(const short8v*)&B2h[r1 * 128 + gk1];
        } else {
            nB0 = qB0; nB1 = qB1;
        }
        __builtin_amdgcn_sched_barrier(0);
        __syncthreads();

        short8v a_h[4], b_h[4];
        #pragma unroll
        for (int f = 0; f < 4; ++f) {
            a_h[f] = *(const short8v*)&AhT[kc * 4096 + aof[f]];
            b_h[f] = *(const short8v*)&Bh[bof[f]];
        }
        #pragma unroll
        for (int mf = 0; mf < 4; ++mf)
            #pragma unroll
            for (int nf = 0; nf < 4; ++nf) {
                acc2[mf][nf] = __builtin_amdgcn_mfma_f32_16x16x32_bf16(a_h[mf], b_h[nf], acc2[mf][nf], 0, 0, 0);
            }
        __syncthreads();
        qB0 = nB0; qB1 = nB1;
    }

    // ---------- epilogue: hWl (bf16) | hWr (f32) ----------
    #pragma unroll
    for (int mf = 0; mf < 4; ++mf)
        #pragma unroll
        for (int nf = 0; nf < 4; ++nf) {
            int col = wn * 64 + nf * 16 + rl;
            #pragma unroll
            for (int i = 0; i < 4; ++i) {
                int row = m0 + wm * 64 + mf * 16 + rq * 4 + i;
                if (row < M) {
                    float v = acc2[mf][nf][i];
                    if (col < 64) hWl[(size_t)row * 64 + col] = bf16_rne(v);
                    else          hWr[(size_t)row * 64 + col - 64] = v;
                }
            }
        }
}

extern "C" void kernel_launch(void* const* d_in, const int* in_sizes, int n_in,
                              void* d_out, int out_size, void* d_ws, size_t ws_size,
                              hipStream_t stream) {
    const float* x   = (const float*)d_in[0];
    const int*   ei  = (const int*)d_in[1];
    const float* W1l = (const float*)d_in[3];
    const float* W1r = (const float*)d_in[4];
    const float* b1  = (const float*)d_in[5];
    const float* W2l = (const float*)d_in[6];
    const float* W2r = (const float*)d_in[7];
    const float* b2  = (const float*)d_in[8];
    float* out = (float*)d_out;

    const int N = N_NODES;
    const int E = in_sizes[1] / 2;     // 1,600,000
    const int* src = ei;
    const int* dst = ei + E;
    const int NEB = (E + ECHUNK - 1) / ECHUNK;   // 196

    // workspace layout (bytes)
    char* ws = (char*)d_ws;
    int*           bhist   = (int*)   (ws + 0);
    int*           boff    = (int*)   (ws + 4096);
    int*           bcur    = (int*)   (ws + 8192);
    int*           offsets = (int*)   (ws + 12288);      // N+1
    float*         invdeg  = (float*) (ws + 417792);     // N
    int*           csr     = (int*)   (ws + 819200);     // E ints (6.4MB)
    unsigned char* ldst    = (unsigned char*)(ws + 7220224);  // E bytes (1.6MB)
    unsigned char* x_f8    = (unsigned char*)(ws + 8821760);  // N*128 fp8 (12.8MB)
    ushort*        x_hi    = (ushort*)(ws + 21622784);   // 25.6MB
    ushort*        agg_hi  = (ushort*)(ws + 47223808);   // 25.6MB
    float*         hWr     = (float*) (ws + 98425856);   // 25.6MB
    ushort*        BT1h    = (ushort*)(ws + 124026880);  // 64KB
    ushort*        BT1l    = (ushort*)(ws + 124092416);
    ushort*        BT2h    = (ushort*)(ws + 124157952);  // 32KB
    // pairs (packed int, 6.4MB) aliases the hWr slot (dead before mfma12 writes hWr)
    int*           pairs   = (int*)   (ws + 98425856);
    // hWl lives in its own slot (must not alias agg: mfma12 reads agg while writing hWl)
    ushort*        hWl     = (ushort*)(ws + 72824832);   // 12.8MB used

    hipMemsetAsync(bhist, 0, NBKT * 4, stream);

    k_prep<<<NXB + NWB + NEB, 256, 0, stream>>>(x, W1l, W1r, W2l, W2r, dst, E,
                                                x_hi, x_f8, BT1h, BT1l, BT2h, bhist);
    kA2_scan<<<1, 512, 0, stream>>>(bhist, boff, bcur);
    kA3_scatter<<<NEB, 256, 0, stream>>>(src, dst, bcur, pairs, E);
    kB_build<<<NBKT, 256, 0, stream>>>(pairs, boff, csr, ldst, offsets, invdeg, N, E);

    k_agg1<<<NGRP, 64, 0, stream>>>(x_f8, csr, ldst, offsets, invdeg, agg_hi, E);

    const int MB = (N + 127) / 128;    // 782
    k_mfma12<<<MB, 256, 0, stream>>>(agg_hi, x_hi, BT1h, BT1l, BT2h,
                                     b1, hWl, hWr, N);

    k_agg2<<<NGRP, 64, 0, stream>>>(hWl, hWr, csr, ldst, offsets, invdeg, b2, out, E);
}